// Round 3
// baseline (879.224 us; speedup 1.0000x reference)
//
#include <hip/hip_runtime.h>
#include <hip/hip_bf16.h>
#include <math.h>

#define B_N 4096
#define M_N 128
#define F_N 32
#define H_N 512
#define NFM 4096   // F*M

// wave-local LDS sync: all lanes of a wave run in lockstep, so a waitcnt on
// outstanding LDS ops makes prior cross-lane LDS writes visible to reads.
#define WAVE_SYNC() do { \
  asm volatile("s_waitcnt lgkmcnt(0)" ::: "memory"); \
  __builtin_amdgcn_sched_barrier(0); \
} while (0)

// ---------------------------------------------------------------------------
// Kernel 1: occupied-index extraction (wave ballot, parallel) + hidden layer
//   h[b,:] = tanhf( sum_j W1[idx_j,:] + b1 )   (ascending-j chain, fp32)
// ---------------------------------------------------------------------------
__global__ __launch_bounds__(256) void k1_idx_h(
    const float* __restrict__ n, const float* __restrict__ W1,
    const float* __restrict__ b1, float* __restrict__ h_ws,
    int* __restrict__ idx_ws)
{
  __shared__ int s_idx[F_N];
  __shared__ int s_cnt0;
  const int b = blockIdx.x;
  const int t = threadIdx.x;

  bool p = false;
  int before = 0;
  if (t < 128) {
    float v = n[(size_t)b * M_N + t];
    p = v > 0.5f;
    unsigned long long m = __ballot(p);
    int lane = t & 63;
    before = __popcll(m & ((1ull << lane) - 1ull));
    if (t < 64) {
      if (lane == 0) s_cnt0 = __popcll(m);
      if (p) s_idx[before] = t;          // ascending within wave 0
    }
  }
  __syncthreads();
  if (t >= 64 && t < 128 && p) s_idx[s_cnt0 + before] = t;
  __syncthreads();

  if (t < F_N) idx_ws[b * F_N + t] = s_idx[t];

  #pragma unroll
  for (int cc = 0; cc < 2; ++cc) {
    int c = t + cc * 256;
    float acc = 0.0f;
    #pragma unroll
    for (int j = 0; j < F_N; ++j)
      acc += W1[(size_t)s_idx[j] * H_N + c];
    acc += b1[c];                        // b1 = zeros: exact
    h_ws[(size_t)b * H_N + c] = tanhf(acc);
  }
}

// ---------------------------------------------------------------------------
// Kernel 2 (ROUND 14 rewrite): GEMM with SGPR-broadcast B — no LDS for B.
// DIAGNOSIS of rounds 0/2: every b128-fragment micro-tile is LDS-pipe-bound:
//   16x8 needs 6 ds_read_b128 (~72 CU-LDS cy, m134: ~12cy each) per kk per
//   wave vs 64 cy/SIMD of fma — ratio >1 at ANY occupancy (both scale with
//   waves). VALUBusy pinned ~60-62% in both rounds.
// FIX: lane = output row, the wave's 32 output cols are WAVE-UNIFORM, so the
//   B operand is scalar per fma. v_fmac_f32 takes one SGPR source -> B lives
//   in SGPRs, loaded from W2 by uniform float4 loads (compiler promotes
//   uniform loads of read-only data to s_load_dwordx4+, merged). Per kk per
//   wave: 1 ds_read_b32 (A, conflict-free: consecutive lanes -> consecutive
//   banks) + 32 fma. LDS demand ~6 cy vs 64 cy VALU -> VALU-bound.
//   Block 256 rows x 32 cols, grid (128 colblocks, 16 rowpanels).
//   LDS 33.8 KB -> 4 blocks/CU = 4 waves/SIMD (2x the latency hiding).
//   A staging UNCHANGED from round 2 (aReg scalar loads -> transposed
//   At[16][260] b128 writes, double-buffered, one barrier per tile).
// ARITHMETIC BIT-IDENTICAL: each output = one ascending-k fmaf chain
//   (tiles ascending, kk ascending, single accumulator); epilogue expression
//   Phi + (bf + b2) unchanged. absmax must stay exactly 0.203125.
// ---------------------------------------------------------------------------
__global__ __launch_bounds__(256, 3) void k2_gemm_gather(
    const float* __restrict__ h, const float* __restrict__ W2,
    const float* __restrict__ b2, const float* __restrict__ Phi,
    const int* __restrict__ idx, float* __restrict__ phi)
{
  // stage: 2 x At[16][260] = 8320 floats; epilogue bf: [256][33] = 8448
  __shared__ __align__(16) float smem[8448];       // 33792 B -> 4 blocks/CU

  const int tid = threadIdx.x;
  const int cb  = blockIdx.x;              // 0..127: column block
  const int rb  = blockIdx.y;              // 0..15 : row panel
  const int ig  = cb >> 2;                 // fermion row 0..31
  const int q   = cb & 3;                  // which 32-col quarter of the 128
  const int c0  = ig * M_N + q * 32;       // global W2/b2 column base
  const int s0  = rb * 256;                // batch row base
  const int row_local = tid;               // one thread == one output row
  const int kA  = tid & 15;                // A stage: kk (0..15)
  const int rbA = (tid >> 4) * 16;         // A stage: row block base (0..240)

  float acc[32];
  #pragma unroll
  for (int c = 0; c < 32; ++c) acc[c] = 0.f;

  float  aReg[16];
  float4 sb[2][8];                         // B row double-buffer (SGPR-hoped)

// uniform W2 row load: 8 x float4 (compiler -> s_load, merged)
#define LOAD_SB(dstp, kglob) do {                                   \
    const float* wp_ = &W2[(size_t)(kglob) * NFM + c0];             \
    _Pragma("unroll")                                               \
    for (int m_ = 0; m_ < 8; ++m_)                                  \
      (dstp)[m_] = *(const float4*)(wp_ + 4 * m_);                  \
  } while (0)

  // ---- prologue: stage A tile 0 into buf0; load B row k=0 ----
  #pragma unroll
  for (int u = 0; u < 4; ++u)
    #pragma unroll
    for (int i = 0; i < 4; ++i)
      aReg[u * 4 + i] = h[(size_t)(s0 + rbA + u * 4 + i) * H_N + kA];
  LOAD_SB(sb[0], 0);
  #pragma unroll
  for (int u = 0; u < 4; ++u)
    *(float4*)&smem[kA * 260 + rbA + u * 4] =
        make_float4(aReg[4 * u], aReg[4 * u + 1], aReg[4 * u + 2], aReg[4 * u + 3]);
  __syncthreads();

  #pragma unroll 1
  for (int t = 0; t < 32; ++t) {
    float* Atc = smem + (t & 1) * 4160;
    float* Atn = smem + ((t + 1) & 1) * 4160;

    // issue next A tile's global loads (latency hides under compute)
    if (t < 31) {
      int k0n = (t + 1) * 16;
      #pragma unroll
      for (int u = 0; u < 4; ++u)
        #pragma unroll
        for (int i = 0; i < 4; ++i)
          aReg[u * 4 + i] = h[(size_t)(s0 + rbA + u * 4 + i) * H_N + k0n + kA];
    }

    // compute tile t: per kk = 1 ds_read_b32 + 32 fma (SGPR B operand);
    // B for kk+1 prefetched into the other sb buffer (depth-2 pipeline)
    #pragma unroll
    for (int kk = 0; kk < 16; ++kk) {
      float aval = Atc[kk * 260 + row_local];
      if (kk < 15) {
        LOAD_SB(sb[(kk + 1) & 1], t * 16 + kk + 1);
      } else if (t < 31) {
        LOAD_SB(sb[0], (t + 1) * 16);    // (15+1)&1 == 0: parity consistent
      }
      const float4* bv = sb[kk & 1];
      #pragma unroll
      for (int m = 0; m < 8; ++m) {
        float4 b4 = bv[m];
        acc[4 * m + 0] = fmaf(aval, b4.x, acc[4 * m + 0]);
        acc[4 * m + 1] = fmaf(aval, b4.y, acc[4 * m + 1]);
        acc[4 * m + 2] = fmaf(aval, b4.z, acc[4 * m + 2]);
        acc[4 * m + 3] = fmaf(aval, b4.w, acc[4 * m + 3]);
      }
    }

    // stage A tile t+1 into the idle buffer; single barrier flips
    if (t < 31) {
      #pragma unroll
      for (int u = 0; u < 4; ++u)
        *(float4*)&Atn[kA * 260 + rbA + u * 4] =
            make_float4(aReg[4 * u], aReg[4 * u + 1], aReg[4 * u + 2], aReg[4 * u + 3]);
      __syncthreads();
    }
  }
#undef LOAD_SB

  // ---- epilogue: acc -> LDS bf[256][33], then idx-gather ----
  __syncthreads();                         // laggard waves may still read buf1
  #pragma unroll
  for (int c = 0; c < 32; ++c)             // banks (row+c)%32: 2-way = free
    smem[row_local * 33 + c] = acc[c];
  __syncthreads();

  #pragma unroll 4
  for (int u = 0; u < 32; ++u) {
    int lin = u * 256 + tid;
    int r = lin >> 5, j = lin & 31;
    int b = s0 + r;
    int c = idx[b * F_N + j];              // 0..127 within this ig
    if ((c >> 5) == q) {                   // exactly one col-block matches
      float val = Phi[ig * M_N + c] + (smem[r * 33 + (c & 31)] + b2[ig * M_N + c]);
      phi[(size_t)b * (F_N * F_N) + ig * F_N + j] = val;
    }
  }
}

// ---------------------------------------------------------------------------
// Kernel 3: batched 32x32 fp32 LU replicating LAPACK sgetf2 exactly.
// Each matrix is owned by ONE wave working in its private LDS slice, so all
// cross-wave __syncthreads() are replaced with wave-local WAVE_SYNC()
// (s_waitcnt lgkmcnt(0)): the 4 waves per block run fully decoupled.
// Arithmetic sequence per matrix UNCHANGED from rounds 6-11.
// PLANAR complex output: out[0..B-1] = log|det|, out[B..2B-1] = arg(sign)
// ---------------------------------------------------------------------------
__global__ __launch_bounds__(256) void k3_det(
    const float* __restrict__ phi, float* __restrict__ out)
{
  __shared__ float A[4][32 * 33];
  const int w = threadIdx.x >> 6;
  const int lane = threadIdx.x & 63;
  const int b = blockIdx.x * 4 + w;
  float* Aw = A[w];

  #pragma unroll
  for (int u = 0; u < 16; ++u) {
    int lin = u * 64 + lane;
    Aw[(lin >> 5) * 33 + (lin & 31)] = phi[(size_t)b * 1024 + lin];
  }
  WAVE_SYNC();

  float logabs = 0.f;
  int negs = 0;
  for (int k = 0; k < 32; ++k) {
    // isamax over rows k..31 of column k (ties -> first index)
    float v = -1.f;
    int vi = lane;
    if (lane >= k && lane < 32) v = fabsf(Aw[lane * 33 + k]);
    #pragma unroll
    for (int off = 32; off > 0; off >>= 1) {
      float ov = __shfl_xor(v, off);
      int oi = __shfl_xor(vi, off);
      if (ov > v || (ov == v && oi < vi)) { v = ov; vi = oi; }
    }
    int p = vi;                          // uniform across the wave
    if (p != k) {
      negs ^= 1;
      if (lane < 32) {
        float tmp = Aw[k * 33 + lane];
        Aw[k * 33 + lane] = Aw[p * 33 + lane];
        Aw[p * 33 + lane] = tmp;
      }
    }
    WAVE_SYNC();
    float piv = Aw[k * 33 + k];
    if (piv < 0.f) negs ^= 1;
    logabs += logf(fabsf(piv));
    if (lane > k && lane < 32) {
      float l = Aw[lane * 33 + k];
      if (fabsf(piv) >= 1.17549435e-38f) l = l * (1.0f / piv);  // sscal path
      else                               l = l / piv;           // tiny pivot
      Aw[lane * 33 + k] = l;
    }
    WAVE_SYNC();
    if (lane > k && lane < 32) {
      int j = lane;
      float nukj = -Aw[k * 33 + j];
      for (int i = k + 1; i < 32; ++i)
        Aw[i * 33 + j] = fmaf(nukj, Aw[i * 33 + k], Aw[i * 33 + j]);
    }
    WAVE_SYNC();
  }

  if (lane == 0) {
    out[b]       = logabs;                                   // Re: log|det|
    out[B_N + b] = (negs & 1) ? 3.14159265358979f : 0.0f;    // Im: arg(sign)
  }
}

// ---------------------------------------------------------------------------
extern "C" void kernel_launch(void* const* d_in, const int* in_sizes, int n_in,
                              void* d_out, int out_size, void* d_ws, size_t ws_size,
                              hipStream_t stream) {
  const float* n   = (const float*)d_in[0];
  const float* Phi = (const float*)d_in[1];
  const float* W1  = (const float*)d_in[2];
  const float* b1  = (const float*)d_in[3];
  const float* W2  = (const float*)d_in[4];
  const float* b2  = (const float*)d_in[5];
  float* out = (float*)d_out;

  char* ws = (char*)d_ws;
  float* h_ws   = (float*)ws;                                   // 8 MB
  int*   idx_ws = (int*)(ws + (size_t)B_N * H_N * 4);           // 512 KB
  float* phi_ws = (float*)(ws + (size_t)B_N * H_N * 4
                              + (size_t)B_N * F_N * 4);         // 16 MB

  hipLaunchKernelGGL(k1_idx_h, dim3(B_N), dim3(256), 0, stream,
                     n, W1, b1, h_ws, idx_ws);
  hipLaunchKernelGGL(k2_gemm_gather, dim3(128, 16), dim3(256), 0, stream,
                     h_ws, W2, b2, Phi, idx_ws, phi_ws);
  hipLaunchKernelGGL(k3_det, dim3(B_N / 4), dim3(256), 0, stream,
                     phi_ws, out);
}

// Round 4
// 303.675 us; speedup vs baseline: 2.8953x; 2.8953x over previous
//
#include <hip/hip_runtime.h>
#include <hip/hip_bf16.h>
#include <math.h>

#define B_N 4096
#define M_N 128
#define F_N 32
#define H_N 512
#define NFM 4096   // F*M

// wave-local LDS sync: all lanes of a wave run in lockstep, so a waitcnt on
// outstanding LDS ops makes prior cross-lane LDS writes visible to reads.
#define WAVE_SYNC() do { \
  asm volatile("s_waitcnt lgkmcnt(0)" ::: "memory"); \
  __builtin_amdgcn_sched_barrier(0); \
} while (0)

// ---------------------------------------------------------------------------
// Kernel 1: occupied-index extraction (wave ballot, parallel) + hidden layer
//   h[b,:] = tanhf( sum_j W1[idx_j,:] + b1 )   (ascending-j chain, fp32)
// ---------------------------------------------------------------------------
__global__ __launch_bounds__(256) void k1_idx_h(
    const float* __restrict__ n, const float* __restrict__ W1,
    const float* __restrict__ b1, float* __restrict__ h_ws,
    int* __restrict__ idx_ws)
{
  __shared__ int s_idx[F_N];
  __shared__ int s_cnt0;
  const int b = blockIdx.x;
  const int t = threadIdx.x;

  bool p = false;
  int before = 0;
  if (t < 128) {
    float v = n[(size_t)b * M_N + t];
    p = v > 0.5f;
    unsigned long long m = __ballot(p);
    int lane = t & 63;
    before = __popcll(m & ((1ull << lane) - 1ull));
    if (t < 64) {
      if (lane == 0) s_cnt0 = __popcll(m);
      if (p) s_idx[before] = t;          // ascending within wave 0
    }
  }
  __syncthreads();
  if (t >= 64 && t < 128 && p) s_idx[s_cnt0 + before] = t;
  __syncthreads();

  if (t < F_N) idx_ws[b * F_N + t] = s_idx[t];

  #pragma unroll
  for (int cc = 0; cc < 2; ++cc) {
    int c = t + cc * 256;
    float acc = 0.0f;
    #pragma unroll
    for (int j = 0; j < F_N; ++j)
      acc += W1[(size_t)s_idx[j] * H_N + c];
    acc += b1[c];                        // b1 = zeros: exact
    h_ws[(size_t)b * H_N + c] = tanhf(acc);
  }
}

// ---------------------------------------------------------------------------
// Kernel 2 (ROUND 15): tiled fp32 GEMM  bf = h @ W2.
// Round 14 (SGPR-broadcast B) FAILED: s_load SMEM latency per kk serialized
// the inner loop (877 us). REVERTED to round-13's LDS micro-tile structure.
// Round 13 post-mortem: grid 512 on 256 CUs = exactly 2 blocks/CU — the GRID
// was the occupancy limit (Occupancy 18.8%), and 4-wave-wide barriers + only
// 2 independent blocks/CU left ~38% issue idle (VALUBusy 62%).
// ROUND 15 reshape: SAME 16x8 micro-tile & BK=16, but 128x128 tile with
// 128-THREAD (2-wave) blocks -> grid 32x32 = 1024 blocks = 4 blocks/CU.
// Same 8 waves/CU, but barriers are 2-wave-wide and 4 independent blocks
// per CU fill each other's barrier-drain stalls. LDS per block 33792 B
// (buffer stride padded to 4224 floats so the epilogue Ds[32][132]=4224
// fits inside buf0, disjoint from buf1 which laggards read for tile 31).
// ARITHMETIC BIT-IDENTICAL: each output = one ascending-k fmaf chain
// (tiles ascending, kk ascending, single accumulator); epilogue expression
// Phi + (Ds + b2) unchanged. absmax must stay exactly 0.203125.
// ---------------------------------------------------------------------------
__global__ __launch_bounds__(128, 2) void k2_gemm_gather(
    const float* __restrict__ h, const float* __restrict__ W2,
    const float* __restrict__ b2, const float* __restrict__ Phi,
    const int* __restrict__ idx, float* __restrict__ phi)
{
  // per buffer: At [16][132] = 2112 floats, Bs [16][128] = 2048, pad to 4224
  __shared__ __align__(16) float smem[2 * 4224];   // 33792 B -> 4 blocks/CU

  const int tid = threadIdx.x;               // 0..127
  const int s0 = blockIdx.x * 128;           // 128 batch rows per block
  const int ig = blockIdx.y;                 // fermion row, 0..31
  const int n0 = ig * 128;
  const int tx = tid & 15;                   // col group: cols tx*4, 64+tx*4
  const int ty = tid >> 4;                   // row group 0..7
  const int kA = tid & 15;                   // A stage: kk (0..15)
  const int rbA = (tid >> 4) * 16;           // A stage: row block base (0..112)
  const int kB = tid >> 5;                   // B stage: k row (0..3)
  const int cB = (tid & 31) * 4;             // B stage: col*4

  float acc[16][8];
  #pragma unroll
  for (int i = 0; i < 16; ++i)
    #pragma unroll
    for (int u = 0; u < 8; ++u) acc[i][u] = 0.f;

  float  aReg[16];
  float4 bReg[4];

  // ---- prologue: stage tile 0 into buf0 ----
  #pragma unroll
  for (int u = 0; u < 4; ++u)
    #pragma unroll
    for (int i = 0; i < 4; ++i)
      aReg[u * 4 + i] = h[(size_t)(s0 + rbA + u * 4 + i) * H_N + kA];
  #pragma unroll
  for (int u = 0; u < 4; ++u)
    bReg[u] = *(const float4*)&W2[(size_t)(kB + 4 * u) * NFM + n0 + cB];
  #pragma unroll
  for (int u = 0; u < 4; ++u)
    *(float4*)&smem[kA * 132 + rbA + u * 4] =
        make_float4(aReg[4 * u], aReg[4 * u + 1], aReg[4 * u + 2], aReg[4 * u + 3]);
  #pragma unroll
  for (int u = 0; u < 4; ++u)
    *(float4*)&smem[2112 + (kB + 4 * u) * 128 + cB] = bReg[u];
  __syncthreads();

  #pragma unroll 1
  for (int t = 0; t < 32; ++t) {
    float* Atc = smem + (t & 1) * 4224;
    float* Bsc = Atc + 2112;
    float* Atn = smem + ((t + 1) & 1) * 4224;
    float* Bsn = Atn + 2112;

    // issue next tile's global loads (latency hides under compute)
    if (t < 31) {
      int k0n = (t + 1) * 16;
      #pragma unroll
      for (int u = 0; u < 4; ++u)
        #pragma unroll
        for (int i = 0; i < 4; ++i)
          aReg[u * 4 + i] = h[(size_t)(s0 + rbA + u * 4 + i) * H_N + k0n + kA];
      #pragma unroll
      for (int u = 0; u < 4; ++u)
        bReg[u] = *(const float4*)&W2[(size_t)(k0n + kB + 4 * u) * NFM + n0 + cB];
    }

    // compute tile t: 6 x ds_read_b128 + 128 fmaf per kk
    #pragma unroll 4
    for (int kk = 0; kk < 16; ++kk) {
      float4 a0 = *(const float4*)&Atc[kk * 132 + ty * 8];
      float4 a1 = *(const float4*)&Atc[kk * 132 + ty * 8 + 4];
      float4 a2 = *(const float4*)&Atc[kk * 132 + 64 + ty * 8];
      float4 a3 = *(const float4*)&Atc[kk * 132 + 64 + ty * 8 + 4];
      float4 b0 = *(const float4*)&Bsc[kk * 128 + tx * 4];
      float4 b1 = *(const float4*)&Bsc[kk * 128 + tx * 4 + 64];
      float a[16] = {a0.x, a0.y, a0.z, a0.w, a1.x, a1.y, a1.z, a1.w,
                     a2.x, a2.y, a2.z, a2.w, a3.x, a3.y, a3.z, a3.w};
      float bb[8] = {b0.x, b0.y, b0.z, b0.w, b1.x, b1.y, b1.z, b1.w};
      #pragma unroll
      for (int i = 0; i < 16; ++i)
        #pragma unroll
        for (int u = 0; u < 8; ++u)
          acc[i][u] = fmaf(a[i], bb[u], acc[i][u]);
    }

    // stage tile t+1 into the idle buffer; single barrier flips
    if (t < 31) {
      #pragma unroll
      for (int u = 0; u < 4; ++u)
        *(float4*)&Atn[kA * 132 + rbA + u * 4] =
            make_float4(aReg[4 * u], aReg[4 * u + 1], aReg[4 * u + 2], aReg[4 * u + 3]);
      #pragma unroll
      for (int u = 0; u < 4; ++u)
        *(float4*)&Bsn[(kB + 4 * u) * 128 + cB] = bReg[u];
      __syncthreads();
    }
  }

  // epilogue: 4 quarters of 32 rows through buf0 (disjoint from buf1, which
  // laggard waves may still be reading for tile 31: 31&1 == 1).
  // Thread rows: i<8 -> ty*8+i (half 0: rows 0..63), i>=8 -> 64+ty*8+(i-8).
  // Quarter q: rows q*32..q*32+31; half = q>>1, owner waves: (ty>>2)==(q&1).
  // q is compile-time (full unroll) so acc stays statically indexed (rule 20).
  float* Ds = smem;                          // [32][132] = 4224 floats = buf0
  #pragma unroll
  for (int q = 0; q < 4; ++q) {
    const int io = (q >> 1) * 8;             // compile-time acc row offset
    if ((ty >> 2) == (q & 1)) {
      int r8 = (ty & 3) * 8;
      #pragma unroll
      for (int i = 0; i < 8; ++i) {
        *(float4*)&Ds[(r8 + i) * 132 + tx * 4] =
            make_float4(acc[io + i][0], acc[io + i][1], acc[io + i][2], acc[io + i][3]);
        *(float4*)&Ds[(r8 + i) * 132 + tx * 4 + 64] =
            make_float4(acc[io + i][4], acc[io + i][5], acc[io + i][6], acc[io + i][7]);
      }
    }
    __syncthreads();
    #pragma unroll
    for (int u = 0; u < 8; ++u) {
      int lin = u * 128 + tid;
      int r = lin >> 5, j = lin & 31;
      int b = s0 + q * 32 + r;
      int c = idx[b * F_N + j];
      float val = Phi[ig * M_N + c] + (Ds[r * 132 + c] + b2[n0 + c]);
      phi[(size_t)b * (F_N * F_N) + ig * F_N + j] = val;
    }
    __syncthreads();
  }
}

// ---------------------------------------------------------------------------
// Kernel 3: batched 32x32 fp32 LU replicating LAPACK sgetf2 exactly.
// Each matrix is owned by ONE wave working in its private LDS slice, so all
// cross-wave __syncthreads() are replaced with wave-local WAVE_SYNC()
// (s_waitcnt lgkmcnt(0)): the 4 waves per block run fully decoupled.
// Arithmetic sequence per matrix UNCHANGED from rounds 6-11.
// PLANAR complex output: out[0..B-1] = log|det|, out[B..2B-1] = arg(sign)
// ---------------------------------------------------------------------------
__global__ __launch_bounds__(256) void k3_det(
    const float* __restrict__ phi, float* __restrict__ out)
{
  __shared__ float A[4][32 * 33];
  const int w = threadIdx.x >> 6;
  const int lane = threadIdx.x & 63;
  const int b = blockIdx.x * 4 + w;
  float* Aw = A[w];

  #pragma unroll
  for (int u = 0; u < 16; ++u) {
    int lin = u * 64 + lane;
    Aw[(lin >> 5) * 33 + (lin & 31)] = phi[(size_t)b * 1024 + lin];
  }
  WAVE_SYNC();

  float logabs = 0.f;
  int negs = 0;
  for (int k = 0; k < 32; ++k) {
    // isamax over rows k..31 of column k (ties -> first index)
    float v = -1.f;
    int vi = lane;
    if (lane >= k && lane < 32) v = fabsf(Aw[lane * 33 + k]);
    #pragma unroll
    for (int off = 32; off > 0; off >>= 1) {
      float ov = __shfl_xor(v, off);
      int oi = __shfl_xor(vi, off);
      if (ov > v || (ov == v && oi < vi)) { v = ov; vi = oi; }
    }
    int p = vi;                          // uniform across the wave
    if (p != k) {
      negs ^= 1;
      if (lane < 32) {
        float tmp = Aw[k * 33 + lane];
        Aw[k * 33 + lane] = Aw[p * 33 + lane];
        Aw[p * 33 + lane] = tmp;
      }
    }
    WAVE_SYNC();
    float piv = Aw[k * 33 + k];
    if (piv < 0.f) negs ^= 1;
    logabs += logf(fabsf(piv));
    if (lane > k && lane < 32) {
      float l = Aw[lane * 33 + k];
      if (fabsf(piv) >= 1.17549435e-38f) l = l * (1.0f / piv);  // sscal path
      else                               l = l / piv;           // tiny pivot
      Aw[lane * 33 + k] = l;
    }
    WAVE_SYNC();
    if (lane > k && lane < 32) {
      int j = lane;
      float nukj = -Aw[k * 33 + j];
      for (int i = k + 1; i < 32; ++i)
        Aw[i * 33 + j] = fmaf(nukj, Aw[i * 33 + k], Aw[i * 33 + j]);
    }
    WAVE_SYNC();
  }

  if (lane == 0) {
    out[b]       = logabs;                                   // Re: log|det|
    out[B_N + b] = (negs & 1) ? 3.14159265358979f : 0.0f;    // Im: arg(sign)
  }
}

// ---------------------------------------------------------------------------
extern "C" void kernel_launch(void* const* d_in, const int* in_sizes, int n_in,
                              void* d_out, int out_size, void* d_ws, size_t ws_size,
                              hipStream_t stream) {
  const float* n   = (const float*)d_in[0];
  const float* Phi = (const float*)d_in[1];
  const float* W1  = (const float*)d_in[2];
  const float* b1  = (const float*)d_in[3];
  const float* W2  = (const float*)d_in[4];
  const float* b2  = (const float*)d_in[5];
  float* out = (float*)d_out;

  char* ws = (char*)d_ws;
  float* h_ws   = (float*)ws;                                   // 8 MB
  int*   idx_ws = (int*)(ws + (size_t)B_N * H_N * 4);           // 512 KB
  float* phi_ws = (float*)(ws + (size_t)B_N * H_N * 4
                              + (size_t)B_N * F_N * 4);         // 16 MB

  hipLaunchKernelGGL(k1_idx_h, dim3(B_N), dim3(256), 0, stream,
                     n, W1, b1, h_ws, idx_ws);
  hipLaunchKernelGGL(k2_gemm_gather, dim3(B_N / 128, F_N), dim3(128), 0, stream,
                     h_ws, W2, b2, Phi, idx_ws, phi_ws);
  hipLaunchKernelGGL(k3_det, dim3(B_N / 4), dim3(256), 0, stream,
                     phi_ws, out);
}